// Round 12
// baseline (594.764 us; speedup 1.0000x reference)
//
#include <hip/hip_runtime.h>

#define CAP 32
#define K 32   // steps per batch; ibuf 16KB + obuf 32KB = 48KB LDS

// ---------------------------------------------------------------------------
// Kernel 1: runtime sparsification of W1 (general; for this input nnz=1/row).
// ---------------------------------------------------------------------------
__global__ void sparsify_kernel(const float* __restrict__ W1, int N,
                                int* __restrict__ cnts, int* __restrict__ cols,
                                float* __restrict__ wts) {
  __shared__ int scnt;
  const int row = blockIdx.x;
  if (threadIdx.x == 0) scnt = 0;
  __syncthreads();
  const float* wr = W1 + (long)row * N;
  for (int k = threadIdx.x; k < N; k += blockDim.x) {
    float w = wr[k];
    if (w != 0.0f) {
      int slot = atomicAdd(&scnt, 1);
      if (slot < CAP) {
        cols[row * CAP + slot] = k;
        wts[row * CAP + slot] = w;
      }
    }
  }
  __syncthreads();
  if (threadIdx.x == 0) {
    cnts[row] = scnt;
    if (scnt == 0) { cols[row * CAP] = 0; wts[row * CAP] = 0.0f; }
  }
}

// ---------------------------------------------------------------------------
// Kernel 3: producer/consumer, R5 compute wave + DISTANCE-2 loader pipeline.
//   R11 isolated the loader's flaw: per-batch global_load -> ds_write of the
//   SAME batch's data exposes full memory latency inside the barrier loop
//   (LLC-warm 300cyc/batch = R5's 333us; HBM-cold 900cyc/batch = R11's 398us;
//   arithmetic matches both measurements exactly).
//   Fix: loader ping-pongs two reg arrays. At batch k it ds_writes batch k+1
//   data loaded during batch k-1 (~3100 cyc earlier >> 900 cyc HBM latency)
//   and issues loads for batch k+2. vmcnt exposure ~0; touch_kernel deleted.
//   Compute wave: EXACT R5 mix (19 insts/step; R8/R10 proved perturbations
//   only hurt). Writers: R5's conflict-free float4 pattern (0 conflicts).
//     wave0 compute (zero global ops) | wave1 loader+s | wave2 v | wave3 u
//   Sync = raw s_barrier + lgkmcnt(0) only; writer stores stay in flight.
// ---------------------------------------------------------------------------
__global__ void __launch_bounds__(256) izh_d2_kernel(
    const float* __restrict__ X, const float* __restrict__ state,
    const float* __restrict__ a, const float* __restrict__ b,
    const float* __restrict__ c, const float* __restrict__ d,
    const float* __restrict__ th, const float* __restrict__ dtv,
    const float* __restrict__ W1,
    const int* __restrict__ cnts, const int* __restrict__ cols,
    const float* __restrict__ wts,
    float* __restrict__ o_s, float* __restrict__ o_st,
    int T, int N)
{
#pragma clang fp contract(off)
  __shared__ float ibuf[2][K][64];        // staged I = w*x   (16 KB)
  __shared__ float obuf[2][K][2][64];     // staged vn,un     (32 KB)
  __shared__ int s_fast;

  const int wid  = threadIdx.x >> 6;
  const int lane = threadIdx.x & 63;
  const int base = blockIdx.x * 64;
  const int gn   = base + lane;
  const long N2  = 2L * N;
  const int B    = T / K;

  // ---- block-uniform path decision ----
  if (wid == 0) {
    bool elig = (base + 64 <= N);
    if (elig) elig = (cnts[gn] == 1) && (dtv[gn] == 1.0f);
    unsigned long long m = __ballot(elig);
    if (lane == 0) s_fast = (m == ~0ULL) ? 1 : 0;
  }
  __syncthreads();

  if (s_fast) {
    // loader's persistent regs (other waves don't touch them)
    float xrA[K], xrB[K];

    // ---- prologue: loader stages batch 0 and issues batch 1 ----
    if (wid == 1) {
      const float wn = wts[gn * CAP];
      const int   c0 = cols[gn * CAP];
      const float* Xp = X + c0;
#pragma unroll
      for (int i = 0; i < K; ++i) xrA[i] = Xp[(size_t)i * N];
#pragma unroll
      for (int i = 0; i < K; ++i) ibuf[0][i][lane] = wn * xrA[i];
      if (B >= 2) {                        // issue batch 1 (retires during sync)
#pragma unroll
        for (int i = 0; i < K; ++i) xrA[i] = Xp[(size_t)(K + i) * N];
      }
    }
    __syncthreads();   // one-time full sync (drains prologue loads)

    if (wid == 0) {
      // ================= compute wave (EXACT R5) =================
      float v = state[gn], u = state[N + gn];
      const float bn = b[gn], cn = c[gn], dn = d[gn], thn = th[gn];
      const float Pn = dtv[gn] * a[gn];   // same operands/order as ref's dt*a

      for (int k = 0; k < B; ++k) {
        const int bsel = k & 1;
#pragma unroll
        for (int i = 0; i < K; ++i) {
          const float I = ibuf[bsel][i][lane];     // 1 ds_read, imm offset
          float t1 = 0.04f * v;
          float t2 = t1 * v;
          float t3 = 5.0f * v;
          float t4 = t2 + t3;
          float t5 = t4 + 140.0f;
          float t6 = t5 - u;
          float t7 = t6 + I;
          float vn = v + t7;      /* dt==1: exact */
          float q1 = bn * v;
          float q2 = q1 - u;
          float q3 = Pn * q2;
          float un = u + q3;
          obuf[bsel][i][0][lane] = vn;             // pre-reset v
          obuf[bsel][i][1][lane] = un;             // pre-jump u
          bool sp = vn > thn;     /* == (vn-thn)>0 bitwise (IEEE) */
          v = sp ? cn : vn;
          u = un + (sp ? dn : 0.0f);
        }
        asm volatile("s_waitcnt lgkmcnt(0)" ::: "memory");
        __builtin_amdgcn_s_barrier();
      }

      // tail (T % K != 0): direct global path (none for T=8192,K=32)
      if (B * K < T) {
        const float w0 = wts[gn * CAP];
        const float* Xp = X + cols[gn * CAP];
        for (int t = B * K; t < T; ++t) {
          const float I = w0 * Xp[(size_t)t * N];
          float t1 = 0.04f * v; float t2 = t1 * v; float t3 = 5.0f * v;
          float t4 = t2 + t3; float t5 = t4 + 140.0f; float t6 = t5 - u;
          float t7 = t6 + I; float vn = v + t7;
          float q1 = bn * v; float q2 = q1 - u; float q3 = Pn * q2;
          float un = u + q3;
          bool sp = vn > thn;
          v = sp ? cn : vn; u = un + (sp ? dn : 0.0f);
          o_s[(long)t * N + gn] = sp ? 1.0f : 0.0f;
          o_st[(long)t * N2 + gn] = v;
          o_st[(long)t * N2 + N + gn] = u;
        }
      }
    } else if (wid == 1) {
      // ========== loader (distance-2 reg pipeline) + s-writer ==========
      const float wn = wts[gn * CAP];
      const int   c0 = cols[gn * CAP];
      const float* Xp = X + c0;
      const int r = lane >> 4, j = lane & 15;
      const float4 th4 = *(const float4*)&th[base + 4 * j];

      // s-store of batch q (reads obuf, coalesced float4 global stores)
#define SSTORE(q)                                                       \
      {                                                                 \
        const int bsel = (q) & 1, t0 = (q) * K;                         \
        _Pragma("unroll")                                               \
        for (int i = 0; i < K; i += 4) {                                \
          float4 vn4 = *(const float4*)&obuf[bsel][i + r][0][4 * j];    \
          float4 s4;                                                    \
          s4.x = vn4.x > th4.x ? 1.0f : 0.0f;                           \
          s4.y = vn4.y > th4.y ? 1.0f : 0.0f;                           \
          s4.z = vn4.z > th4.z ? 1.0f : 0.0f;                           \
          s4.w = vn4.w > th4.w ? 1.0f : 0.0f;                           \
          *(float4*)(o_s + (size_t)(t0 + i + r) * N + base + 4 * j) = s4; \
        }                                                               \
      }

      for (int k = 0; k < B; ++k) {
        if ((k & 1) == 0) {
          // write batch k+1 (loaded at k-1, long retired); issue batch k+2
          if (k + 1 < B) {
#pragma unroll
            for (int i = 0; i < K; ++i) ibuf[(k + 1) & 1][i][lane] = wn * xrA[i];
          }
          if (k + 2 < B) {
#pragma unroll
            for (int i = 0; i < K; ++i)
              xrB[i] = Xp[(size_t)((k + 2) * K + i) * N];
          }
        } else {
          if (k + 1 < B) {
#pragma unroll
            for (int i = 0; i < K; ++i) ibuf[(k + 1) & 1][i][lane] = wn * xrB[i];
          }
          if (k + 2 < B) {
#pragma unroll
            for (int i = 0; i < K; ++i)
              xrA[i] = Xp[(size_t)((k + 2) * K + i) * N];
          }
        }
        if (k > 0) SSTORE(k - 1)
        asm volatile("s_waitcnt lgkmcnt(0)" ::: "memory");
        __builtin_amdgcn_s_barrier();
      }
      if (B > 0) SSTORE(B - 1)             // drain last staged batch
#undef SSTORE
    } else if (wid == 2) {
      // ================= v-writer: v_out = sp ? c : vn =================
      const int r = lane >> 4, j = lane & 15;
      const float4 th4 = *(const float4*)&th[base + 4 * j];
      const float4 c4  = *(const float4*)&c[base + 4 * j];

      for (int k = 0; k < B; ++k) {
        if (k > 0) {
          const int q = k - 1, bsel = q & 1, t0 = q * K;
#pragma unroll
          for (int i = 0; i < K; i += 4) {
            float4 vn4 = *(const float4*)&obuf[bsel][i + r][0][4 * j];
            float4 o4;
            o4.x = vn4.x > th4.x ? c4.x : vn4.x;
            o4.y = vn4.y > th4.y ? c4.y : vn4.y;
            o4.z = vn4.z > th4.z ? c4.z : vn4.z;
            o4.w = vn4.w > th4.w ? c4.w : vn4.w;
            *(float4*)(o_st + (size_t)(t0 + i + r) * N2 + base + 4 * j) = o4;
          }
        }
        __builtin_amdgcn_s_barrier();
      }
      if (B > 0) {
        const int q = B - 1, bsel = q & 1, t0 = q * K;
#pragma unroll
        for (int i = 0; i < K; i += 4) {
          float4 vn4 = *(const float4*)&obuf[bsel][i + r][0][4 * j];
          float4 o4;
          o4.x = vn4.x > th4.x ? c4.x : vn4.x;
          o4.y = vn4.y > th4.y ? c4.y : vn4.y;
          o4.z = vn4.z > th4.z ? c4.z : vn4.z;
          o4.w = vn4.w > th4.w ? c4.w : vn4.w;
          *(float4*)(o_st + (size_t)(t0 + i + r) * N2 + base + 4 * j) = o4;
        }
      }
    } else {
      // ================= u-writer: u_out = un + (sp ? d : 0) =============
      const int r = lane >> 4, j = lane & 15;
      const float4 th4 = *(const float4*)&th[base + 4 * j];
      const float4 d4  = *(const float4*)&d[base + 4 * j];

      for (int k = 0; k < B; ++k) {
        if (k > 0) {
          const int q = k - 1, bsel = q & 1, t0 = q * K;
#pragma unroll
          for (int i = 0; i < K; i += 4) {
            float4 vn4 = *(const float4*)&obuf[bsel][i + r][0][4 * j];
            float4 un4 = *(const float4*)&obuf[bsel][i + r][1][4 * j];
            float4 o4;
            o4.x = un4.x + (vn4.x > th4.x ? d4.x : 0.0f);
            o4.y = un4.y + (vn4.y > th4.y ? d4.y : 0.0f);
            o4.z = un4.z + (vn4.z > th4.z ? d4.z : 0.0f);
            o4.w = un4.w + (vn4.w > th4.w ? d4.w : 0.0f);
            *(float4*)(o_st + (size_t)(t0 + i + r) * N2 + N + base + 4 * j) = o4;
          }
        }
        __builtin_amdgcn_s_barrier();
      }
      if (B > 0) {
        const int q = B - 1, bsel = q & 1, t0 = q * K;
#pragma unroll
        for (int i = 0; i < K; i += 4) {
          float4 vn4 = *(const float4*)&obuf[bsel][i + r][0][4 * j];
          float4 un4 = *(const float4*)&obuf[bsel][i + r][1][4 * j];
          float4 o4;
          o4.x = un4.x + (vn4.x > th4.x ? d4.x : 0.0f);
          o4.y = un4.y + (vn4.y > th4.y ? d4.y : 0.0f);
          o4.z = un4.z + (vn4.z > th4.z ? d4.z : 0.0f);
          o4.w = un4.w + (vn4.w > th4.w ? d4.w : 0.0f);
          *(float4*)(o_st + (size_t)(t0 + i + r) * N2 + N + base + 4 * j) = o4;
        }
      }
    }
  } else {
    // ---- general fallback: wave0 threads only, any cnt / dt ----
    if (wid != 0 || gn >= N) return;
    float v = state[gn], u = state[N + gn];
    const float an = a[gn], bn = b[gn], cn = c[gn], dn = d[gn];
    const float thn = th[gn], dtn = dtv[gn];
    const float Pn = dtn * an;
    const int cnt = cnts[gn];
    for (int t = 0; t < T; ++t) {
      float I = 0.0f;
      if (cnt <= CAP) {
        for (int j = 0; j < cnt; ++j)
          I = I + wts[gn * CAP + j] * X[(size_t)t * N + cols[gn * CAP + j]];
      } else {
        const float* wr = W1 + (size_t)gn * N;
        const float* xr = X + (size_t)t * N;
        for (int kk = 0; kk < N; ++kk) I = I + wr[kk] * xr[kk];
      }
      float t1 = 0.04f * v; float t2 = t1 * v; float t3 = 5.0f * v;
      float t4 = t2 + t3; float t5 = t4 + 140.0f; float t6 = t5 - u;
      float t7 = t6 + I; float t8 = dtn * t7; float vn = v + t8;
      float q1 = bn * v; float q2 = q1 - u; float q3 = Pn * q2; float un = u + q3;
      float df = vn - thn; bool sp = df > 0.0f;
      v = sp ? cn : vn; u = un + (sp ? dn : 0.0f);
      o_s[(size_t)t * N + gn] = sp ? 1.0f : 0.0f;
      o_st[(size_t)t * N2 + gn] = v;
      o_st[(size_t)t * N2 + N + gn] = u;
    }
  }
}

// ---------------------------------------------------------------------------
// Kernel 4: r[t] = W2 @ s[t], grid-stride over t (exact: terms are 20*{0,1},
// integer sums < 2^24 are order-independent).
// ---------------------------------------------------------------------------
__global__ void decode_dot_kernel(const float* __restrict__ o_s,
                                  const float* __restrict__ W2,
                                  float* __restrict__ r, int T, int N) {
  __shared__ float red[4];
  for (int t = blockIdx.x; t < T; t += gridDim.x) {
    const float* srow = o_s + (long)t * N;
    float p = 0.0f;
    for (int n = threadIdx.x; n < N; n += blockDim.x)
      p += W2[n] * srow[n];
    for (int off = 32; off > 0; off >>= 1) p += __shfl_down(p, off);
    if ((threadIdx.x & 63) == 0) red[threadIdx.x >> 6] = p;
    __syncthreads();
    if (threadIdx.x == 0) {
      float tot = 0.f;
      const int nw = blockDim.x >> 6;
      for (int w = 0; w < nw; ++w) tot += red[w];
      r[t] = tot;
    }
    __syncthreads();
  }
}

// ---------------------------------------------------------------------------
// Kernel 5: dm[t] = leak*dm[t-1] + r[t], chunked affine scan (1 block, 64 thr)
// ---------------------------------------------------------------------------
__global__ void decode_scan_kernel(const float* __restrict__ r,
                                   const float* __restrict__ leakp,
                                   float* __restrict__ out, int T) {
  __shared__ float Bsh[64], Ssh[64];
  const float leakv = leakp[0];
  const int i = threadIdx.x;                 // 0..63
  const int chunk = (T + 63) / 64;
  const int t0 = i * chunk;
  float B = 0.0f;
  for (int j = 0; j < chunk; ++j) {
    int t = t0 + j;
    if (t < T) B = leakv * B + r[t];
  }
  Bsh[i] = B;
  float A = 1.0f, p = leakv; int e = chunk;
  while (e) { if (e & 1) A *= p; p *= p; e >>= 1; }
  __syncthreads();
  if (i == 0) {
    float dm = 0.0f;
    for (int k = 0; k < 64; ++k) { Ssh[k] = dm; dm = A * dm + Bsh[k]; }
  }
  __syncthreads();
  float dm = Ssh[i];
  for (int j = 0; j < chunk; ++j) {
    int t = t0 + j;
    if (t < T) { dm = leakv * dm + r[t]; out[t] = dm; }
  }
}

// ---------------------------------------------------------------------------
extern "C" void kernel_launch(void* const* d_in, const int* in_sizes, int n_in,
                              void* d_out, int out_size, void* d_ws, size_t ws_size,
                              hipStream_t stream) {
  const float* X  = (const float*)d_in[0];
  const float* st = (const float*)d_in[1];
  const float* W1 = (const float*)d_in[2];
  const float* W2 = (const float*)d_in[3];
  const float* a  = (const float*)d_in[4];
  const float* b  = (const float*)d_in[5];
  const float* c  = (const float*)d_in[6];
  const float* d  = (const float*)d_in[7];
  const float* th = (const float*)d_in[8];
  const float* dt = (const float*)d_in[9];
  const float* lk = (const float*)d_in[10];
  const int N = in_sizes[4];          // a has N elements
  const int T = in_sizes[0] / N;

  float* o_s  = (float*)d_out;               // outputs  [T,N]
  float* o_st = o_s + (long)T * N;           // states   [T,2,N]
  float* o_dm = o_st + 2L * (long)T * N;     // decoded  [T,1]

  int*   cnts = (int*)d_ws;                  // N
  int*   cols = cnts + N;                    // N*CAP
  float* wts  = (float*)(cols + (long)N * CAP); // N*CAP
  float* rbuf = wts + (long)N * CAP;         // T

  sparsify_kernel<<<N, 256, 0, stream>>>(W1, N, cnts, cols, wts);
  const int nblk = (N + 63) / 64;
  izh_d2_kernel<<<nblk, 256, 0, stream>>>(X, st, a, b, c, d, th, dt, W1,
                                          cnts, cols, wts, o_s, o_st, T, N);
  const int ndec = (T < 2048) ? T : 2048;
  decode_dot_kernel<<<ndec, 256, 0, stream>>>(o_s, W2, rbuf, T, N);
  decode_scan_kernel<<<1, 64, 0, stream>>>(rbuf, lk, o_dm, T);
}

// Round 13
// 511.841 us; speedup vs baseline: 1.1620x; 1.1620x over previous
//
#include <hip/hip_runtime.h>

#define CAP 32
#define K 32   // steps per batch; ibuf 16KB + obuf 32KB = 48KB LDS

// ---------------------------------------------------------------------------
// Kernel 1: runtime sparsification of W1 (general; for this input nnz=1/row).
// ---------------------------------------------------------------------------
__global__ void sparsify_kernel(const float* __restrict__ W1, int N,
                                int* __restrict__ cnts, int* __restrict__ cols,
                                float* __restrict__ wts) {
  __shared__ int scnt;
  const int row = blockIdx.x;
  if (threadIdx.x == 0) scnt = 0;
  __syncthreads();
  const float* wr = W1 + (long)row * N;
  for (int k = threadIdx.x; k < N; k += blockDim.x) {
    float w = wr[k];
    if (w != 0.0f) {
      int slot = atomicAdd(&scnt, 1);
      if (slot < CAP) {
        cols[row * CAP + slot] = k;
        wts[row * CAP + slot] = w;
      }
    }
  }
  __syncthreads();
  if (threadIdx.x == 0) {
    cnts[row] = scnt;
    if (scnt == 0) { cols[row * CAP] = 0; wts[row * CAP] = 0.0f; }
  }
}

// ---------------------------------------------------------------------------
// Kernel 2: warm input_batch into LLC. PROVEN NECESSARY (R5 vs R11 A/B):
// identical izh kernel measured 333us with touch, 398us without — exactly
// the LLC-warm (300cyc) vs HBM-cold (900cyc) per-batch loader wait, x256
// batches. Source-level distance-2 prefetch (R12) cannot replace it: the
// compiler refuses to hold 64 floats live (VGPR stayed 68) and re-fuses
// load->ds_write, re-exposing the latency. The touch kernel costs ~20us
// and saves ~65us on the critical kernel.
// ---------------------------------------------------------------------------
__global__ void touch_kernel(const float4* __restrict__ x4, long n4,
                             float* __restrict__ dump) {
  long i = (long)blockIdx.x * blockDim.x + threadIdx.x;
  const long stride = (long)gridDim.x * blockDim.x;
  float acc = 0.f;
  for (; i < n4; i += stride) {
    float4 v = x4[i];
    acc += v.x + v.y + v.z + v.w;
  }
  if (acc == 1234.56789f) dump[blockIdx.x & 1023] = acc;  // defeat DCE
}

// ---------------------------------------------------------------------------
// Kernel 3: producer/consumer, minimal-instruction compute wave.
//   EXACT R5 structure (measured 333 us; best of 12 experiments).
//   Perturbation ledger: VOP3P packed (R8) 405; b64+K64 (R10) 363; f32x2
//   obuf (R7) 440 [4-way bank conflict]; fused decode (R9) 1507 [atomic
//   contention on barrier-coupled wave]. R5's mix is the local optimum.
//     wave0 (compute): 16 VALU + 1 ds_read_b32 (I) + 2 ds_write_b32 = 19/step
//       at the measured ~5.1 cyc/inst solo-wave cadence -> ~98 cyc/step.
//       - I = w*x precomputed by the loader, read via imm-offset ds_read.
//       - Writes PRE-reset vn and PRE-jump un; writers re-derive the spike.
//       - sp = (vn > thn) is bitwise-equivalent to ((vn-thn) > 0) in IEEE.
//     wave1 (loader + s-writer): loads x (LLC-warm via touch), I=w*x -> ibuf
//       (dbuf, one batch ahead); recomputes s from obuf.vn and stores.
//     wave2 (v-writer): v_out = sp ? c : vn.   wave3 (u-writer): un + sp?d:0.
//   All LDS conflict-free (measured 0): scalar planes, float4 reads at 16B
//   stride (32B stride = 4-way conflict, R7's bug).
//   Sync = raw s_barrier + lgkmcnt(0) only; writer stores stay in flight.
// ---------------------------------------------------------------------------
__global__ void __launch_bounds__(256) izh_pc3_kernel(
    const float* __restrict__ X, const float* __restrict__ state,
    const float* __restrict__ a, const float* __restrict__ b,
    const float* __restrict__ c, const float* __restrict__ d,
    const float* __restrict__ th, const float* __restrict__ dtv,
    const float* __restrict__ W1,
    const int* __restrict__ cnts, const int* __restrict__ cols,
    const float* __restrict__ wts,
    float* __restrict__ o_s, float* __restrict__ o_st,
    int T, int N)
{
#pragma clang fp contract(off)
  __shared__ float ibuf[2][K][64];        // staged I = w*x   (16 KB)
  __shared__ float obuf[2][K][2][64];     // staged vn,un     (32 KB)
  __shared__ int s_fast;

  const int wid  = threadIdx.x >> 6;
  const int lane = threadIdx.x & 63;
  const int base = blockIdx.x * 64;
  const int gn   = base + lane;
  const long N2  = 2L * N;
  const int B    = T / K;

  // ---- block-uniform path decision ----
  if (wid == 0) {
    bool elig = (base + 64 <= N);
    if (elig) elig = (cnts[gn] == 1) && (dtv[gn] == 1.0f);
    unsigned long long m = __ballot(elig);
    if (lane == 0) s_fast = (m == ~0ULL) ? 1 : 0;
  }
  __syncthreads();

  if (s_fast) {
    // ---- prologue: loader fills ibuf[0] (batch 0) ----
    if (wid == 1) {
      const float wn = wts[gn * CAP];
      const int   c0 = cols[gn * CAP];
      const float* Xp = X + c0;
      float xr[K];
#pragma unroll
      for (int i = 0; i < K; ++i) xr[i] = Xp[(size_t)i * N];
#pragma unroll
      for (int i = 0; i < K; ++i) ibuf[0][i][lane] = wn * xr[i];
    }
    __syncthreads();   // one-time full sync (vmcnt drain OK outside loop)

    if (wid == 0) {
      // ================= compute wave =================
      float v = state[gn], u = state[N + gn];
      const float bn = b[gn], cn = c[gn], dn = d[gn], thn = th[gn];
      const float Pn = dtv[gn] * a[gn];   // same operands/order as ref's dt*a

      for (int k = 0; k < B; ++k) {
        const int bsel = k & 1;
#pragma unroll
        for (int i = 0; i < K; ++i) {
          const float I = ibuf[bsel][i][lane];     // 1 ds_read, imm offset
          float t1 = 0.04f * v;
          float t2 = t1 * v;
          float t3 = 5.0f * v;
          float t4 = t2 + t3;
          float t5 = t4 + 140.0f;
          float t6 = t5 - u;
          float t7 = t6 + I;
          float vn = v + t7;      /* dt==1: exact */
          float q1 = bn * v;
          float q2 = q1 - u;
          float q3 = Pn * q2;
          float un = u + q3;
          obuf[bsel][i][0][lane] = vn;             // pre-reset v
          obuf[bsel][i][1][lane] = un;             // pre-jump u
          bool sp = vn > thn;     /* == (vn-thn)>0 bitwise (IEEE) */
          v = sp ? cn : vn;
          u = un + (sp ? dn : 0.0f);
        }
        asm volatile("s_waitcnt lgkmcnt(0)" ::: "memory");
        __builtin_amdgcn_s_barrier();
      }

      // tail (T % K != 0): direct global path (none for T=8192,K=32)
      if (B * K < T) {
        const float w0 = wts[gn * CAP];
        const float* Xp = X + cols[gn * CAP];
        for (int t = B * K; t < T; ++t) {
          const float I = w0 * Xp[(size_t)t * N];
          float t1 = 0.04f * v; float t2 = t1 * v; float t3 = 5.0f * v;
          float t4 = t2 + t3; float t5 = t4 + 140.0f; float t6 = t5 - u;
          float t7 = t6 + I; float vn = v + t7;
          float q1 = bn * v; float q2 = q1 - u; float q3 = Pn * q2;
          float un = u + q3;
          bool sp = vn > thn;
          v = sp ? cn : vn; u = un + (sp ? dn : 0.0f);
          o_s[(long)t * N + gn] = sp ? 1.0f : 0.0f;
          o_st[(long)t * N2 + gn] = v;
          o_st[(long)t * N2 + N + gn] = u;
        }
      }
    } else if (wid == 1) {
      // ================= loader + s-writer =================
      const float wn = wts[gn * CAP];
      const int   c0 = cols[gn * CAP];
      const float* Xp = X + c0;
      const int r = lane >> 4, j = lane & 15;
      const float4 th4 = *(const float4*)&th[base + 4 * j];

      for (int k = 0; k < B; ++k) {
        if (k + 1 < B) {                    // stage I for batch k+1
          float xr[K];
#pragma unroll
          for (int i = 0; i < K; ++i) xr[i] = Xp[(size_t)((k + 1) * K + i) * N];
#pragma unroll
          for (int i = 0; i < K; ++i) ibuf[(k + 1) & 1][i][lane] = wn * xr[i];
        }
        if (k > 0) {                        // s-store batch k-1
          const int q = k - 1, bsel = q & 1, t0 = q * K;
#pragma unroll
          for (int i = 0; i < K; i += 4) {
            float4 vn4 = *(const float4*)&obuf[bsel][i + r][0][4 * j];
            float4 s4;
            s4.x = vn4.x > th4.x ? 1.0f : 0.0f;
            s4.y = vn4.y > th4.y ? 1.0f : 0.0f;
            s4.z = vn4.z > th4.z ? 1.0f : 0.0f;
            s4.w = vn4.w > th4.w ? 1.0f : 0.0f;
            *(float4*)(o_s + (size_t)(t0 + i + r) * N + base + 4 * j) = s4;
          }
        }
        asm volatile("s_waitcnt lgkmcnt(0)" ::: "memory");
        __builtin_amdgcn_s_barrier();
      }
      if (B > 0) {                          // drain s for batch B-1
        const int q = B - 1, bsel = q & 1, t0 = q * K;
#pragma unroll
        for (int i = 0; i < K; i += 4) {
          float4 vn4 = *(const float4*)&obuf[bsel][i + r][0][4 * j];
          float4 s4;
          s4.x = vn4.x > th4.x ? 1.0f : 0.0f;
          s4.y = vn4.y > th4.y ? 1.0f : 0.0f;
          s4.z = vn4.z > th4.z ? 1.0f : 0.0f;
          s4.w = vn4.w > th4.w ? 1.0f : 0.0f;
          *(float4*)(o_s + (size_t)(t0 + i + r) * N + base + 4 * j) = s4;
        }
      }
    } else if (wid == 2) {
      // ================= v-writer: v_out = sp ? c : vn =================
      const int r = lane >> 4, j = lane & 15;
      const float4 th4 = *(const float4*)&th[base + 4 * j];
      const float4 c4  = *(const float4*)&c[base + 4 * j];

      for (int k = 0; k < B; ++k) {
        if (k > 0) {
          const int q = k - 1, bsel = q & 1, t0 = q * K;
#pragma unroll
          for (int i = 0; i < K; i += 4) {
            float4 vn4 = *(const float4*)&obuf[bsel][i + r][0][4 * j];
            float4 o4;
            o4.x = vn4.x > th4.x ? c4.x : vn4.x;
            o4.y = vn4.y > th4.y ? c4.y : vn4.y;
            o4.z = vn4.z > th4.z ? c4.z : vn4.z;
            o4.w = vn4.w > th4.w ? c4.w : vn4.w;
            *(float4*)(o_st + (size_t)(t0 + i + r) * N2 + base + 4 * j) = o4;
          }
        }
        __builtin_amdgcn_s_barrier();
      }
      if (B > 0) {
        const int q = B - 1, bsel = q & 1, t0 = q * K;
#pragma unroll
        for (int i = 0; i < K; i += 4) {
          float4 vn4 = *(const float4*)&obuf[bsel][i + r][0][4 * j];
          float4 o4;
          o4.x = vn4.x > th4.x ? c4.x : vn4.x;
          o4.y = vn4.y > th4.y ? c4.y : vn4.y;
          o4.z = vn4.z > th4.z ? c4.z : vn4.z;
          o4.w = vn4.w > th4.w ? c4.w : vn4.w;
          *(float4*)(o_st + (size_t)(t0 + i + r) * N2 + base + 4 * j) = o4;
        }
      }
    } else {
      // ================= u-writer: u_out = un + (sp ? d : 0) =============
      const int r = lane >> 4, j = lane & 15;
      const float4 th4 = *(const float4*)&th[base + 4 * j];
      const float4 d4  = *(const float4*)&d[base + 4 * j];

      for (int k = 0; k < B; ++k) {
        if (k > 0) {
          const int q = k - 1, bsel = q & 1, t0 = q * K;
#pragma unroll
          for (int i = 0; i < K; i += 4) {
            float4 vn4 = *(const float4*)&obuf[bsel][i + r][0][4 * j];
            float4 un4 = *(const float4*)&obuf[bsel][i + r][1][4 * j];
            float4 o4;
            o4.x = un4.x + (vn4.x > th4.x ? d4.x : 0.0f);
            o4.y = un4.y + (vn4.y > th4.y ? d4.y : 0.0f);
            o4.z = un4.z + (vn4.z > th4.z ? d4.z : 0.0f);
            o4.w = un4.w + (vn4.w > th4.w ? d4.w : 0.0f);
            *(float4*)(o_st + (size_t)(t0 + i + r) * N2 + N + base + 4 * j) = o4;
          }
        }
        __builtin_amdgcn_s_barrier();
      }
      if (B > 0) {
        const int q = B - 1, bsel = q & 1, t0 = q * K;
#pragma unroll
        for (int i = 0; i < K; i += 4) {
          float4 vn4 = *(const float4*)&obuf[bsel][i + r][0][4 * j];
          float4 un4 = *(const float4*)&obuf[bsel][i + r][1][4 * j];
          float4 o4;
          o4.x = un4.x + (vn4.x > th4.x ? d4.x : 0.0f);
          o4.y = un4.y + (vn4.y > th4.y ? d4.y : 0.0f);
          o4.z = un4.z + (vn4.z > th4.z ? d4.z : 0.0f);
          o4.w = un4.w + (vn4.w > th4.w ? d4.w : 0.0f);
          *(float4*)(o_st + (size_t)(t0 + i + r) * N2 + N + base + 4 * j) = o4;
        }
      }
    }
  } else {
    // ---- general fallback: wave0 threads only, any cnt / dt ----
    if (wid != 0 || gn >= N) return;
    float v = state[gn], u = state[N + gn];
    const float an = a[gn], bn = b[gn], cn = c[gn], dn = d[gn];
    const float thn = th[gn], dtn = dtv[gn];
    const float Pn = dtn * an;
    const int cnt = cnts[gn];
    for (int t = 0; t < T; ++t) {
      float I = 0.0f;
      if (cnt <= CAP) {
        for (int j = 0; j < cnt; ++j)
          I = I + wts[gn * CAP + j] * X[(size_t)t * N + cols[gn * CAP + j]];
      } else {
        const float* wr = W1 + (size_t)gn * N;
        const float* xr = X + (size_t)t * N;
        for (int kk = 0; kk < N; ++kk) I = I + wr[kk] * xr[kk];
      }
      float t1 = 0.04f * v; float t2 = t1 * v; float t3 = 5.0f * v;
      float t4 = t2 + t3; float t5 = t4 + 140.0f; float t6 = t5 - u;
      float t7 = t6 + I; float t8 = dtn * t7; float vn = v + t8;
      float q1 = bn * v; float q2 = q1 - u; float q3 = Pn * q2; float un = u + q3;
      float df = vn - thn; bool sp = df > 0.0f;
      v = sp ? cn : vn; u = un + (sp ? dn : 0.0f);
      o_s[(size_t)t * N + gn] = sp ? 1.0f : 0.0f;
      o_st[(size_t)t * N2 + gn] = v;
      o_st[(size_t)t * N2 + N + gn] = u;
    }
  }
}

// ---------------------------------------------------------------------------
// Kernel 4: r[t] = W2 @ s[t], grid-stride over t (exact: terms are 20*{0,1},
// integer sums < 2^24 are order-independent).
// ---------------------------------------------------------------------------
__global__ void decode_dot_kernel(const float* __restrict__ o_s,
                                  const float* __restrict__ W2,
                                  float* __restrict__ r, int T, int N) {
  __shared__ float red[4];
  for (int t = blockIdx.x; t < T; t += gridDim.x) {
    const float* srow = o_s + (long)t * N;
    float p = 0.0f;
    for (int n = threadIdx.x; n < N; n += blockDim.x)
      p += W2[n] * srow[n];
    for (int off = 32; off > 0; off >>= 1) p += __shfl_down(p, off);
    if ((threadIdx.x & 63) == 0) red[threadIdx.x >> 6] = p;
    __syncthreads();
    if (threadIdx.x == 0) {
      float tot = 0.f;
      const int nw = blockDim.x >> 6;
      for (int w = 0; w < nw; ++w) tot += red[w];
      r[t] = tot;
    }
    __syncthreads();
  }
}

// ---------------------------------------------------------------------------
// Kernel 5: dm[t] = leak*dm[t-1] + r[t], chunked affine scan (1 block, 64 thr)
// ---------------------------------------------------------------------------
__global__ void decode_scan_kernel(const float* __restrict__ r,
                                   const float* __restrict__ leakp,
                                   float* __restrict__ out, int T) {
  __shared__ float Bsh[64], Ssh[64];
  const float leakv = leakp[0];
  const int i = threadIdx.x;                 // 0..63
  const int chunk = (T + 63) / 64;
  const int t0 = i * chunk;
  float B = 0.0f;
  for (int j = 0; j < chunk; ++j) {
    int t = t0 + j;
    if (t < T) B = leakv * B + r[t];
  }
  Bsh[i] = B;
  float A = 1.0f, p = leakv; int e = chunk;
  while (e) { if (e & 1) A *= p; p *= p; e >>= 1; }
  __syncthreads();
  if (i == 0) {
    float dm = 0.0f;
    for (int k = 0; k < 64; ++k) { Ssh[k] = dm; dm = A * dm + Bsh[k]; }
  }
  __syncthreads();
  float dm = Ssh[i];
  for (int j = 0; j < chunk; ++j) {
    int t = t0 + j;
    if (t < T) { dm = leakv * dm + r[t]; out[t] = dm; }
  }
}

// ---------------------------------------------------------------------------
extern "C" void kernel_launch(void* const* d_in, const int* in_sizes, int n_in,
                              void* d_out, int out_size, void* d_ws, size_t ws_size,
                              hipStream_t stream) {
  const float* X  = (const float*)d_in[0];
  const float* st = (const float*)d_in[1];
  const float* W1 = (const float*)d_in[2];
  const float* W2 = (const float*)d_in[3];
  const float* a  = (const float*)d_in[4];
  const float* b  = (const float*)d_in[5];
  const float* c  = (const float*)d_in[6];
  const float* d  = (const float*)d_in[7];
  const float* th = (const float*)d_in[8];
  const float* dt = (const float*)d_in[9];
  const float* lk = (const float*)d_in[10];
  const int N = in_sizes[4];          // a has N elements
  const int T = in_sizes[0] / N;

  float* o_s  = (float*)d_out;               // outputs  [T,N]
  float* o_st = o_s + (long)T * N;           // states   [T,2,N]
  float* o_dm = o_st + 2L * (long)T * N;     // decoded  [T,1]

  int*   cnts = (int*)d_ws;                  // N
  int*   cols = cnts + N;                    // N*CAP
  float* wts  = (float*)(cols + (long)N * CAP); // N*CAP
  float* rbuf = wts + (long)N * CAP;         // T
  float* dump = rbuf + T;                    // toucher sink

  sparsify_kernel<<<N, 256, 0, stream>>>(W1, N, cnts, cols, wts);
  const long n4 = ((long)T * N) / 4;
  touch_kernel<<<1024, 256, 0, stream>>>((const float4*)X, n4, dump);
  const int nblk = (N + 63) / 64;
  izh_pc3_kernel<<<nblk, 256, 0, stream>>>(X, st, a, b, c, d, th, dt, W1,
                                           cnts, cols, wts, o_s, o_st, T, N);
  const int ndec = (T < 2048) ? T : 2048;
  decode_dot_kernel<<<ndec, 256, 0, stream>>>(o_s, W2, rbuf, T, N);
  decode_scan_kernel<<<1, 64, 0, stream>>>(rbuf, lk, o_dm, T);
}

// Round 14
// 510.022 us; speedup vs baseline: 1.1662x; 1.0036x over previous
//
#include <hip/hip_runtime.h>

#define CAP 32
#define K 32   // steps per batch; ibuf 16KB + obuf 32KB = 48KB LDS

// ---------------------------------------------------------------------------
// Kernel 1: sparsify W1 (nnz extraction per row) MERGED with the X LLC-warm
// pass. Both are pre-izh with grid N x 256; merging deletes one dispatch and
// overlaps W1's 4MB read with X's 32MB read (bound by max, not sum).
// Touch is PROVEN NECESSARY (R5 vs R11 A/B: identical izh kernel = 333us
// LLC-warm vs 398us HBM-cold = 300 vs 900 cyc/batch loader wait x 256).
// Source-level distance-2 prefetch (R12) cannot replace it: the compiler
// refuses to hold 64 floats live (VGPR stayed 68) and re-fuses the
// load->ds_write, re-exposing the latency.
// ---------------------------------------------------------------------------
__global__ void sparsify_touch_kernel(const float* __restrict__ W1, int N,
                                      int* __restrict__ cnts,
                                      int* __restrict__ cols,
                                      float* __restrict__ wts,
                                      const float4* __restrict__ x4, long n4,
                                      float* __restrict__ dump) {
  __shared__ int scnt;
  const int row = blockIdx.x;
  if (threadIdx.x == 0) scnt = 0;
  __syncthreads();
  if (row < N) {
    const float* wr = W1 + (long)row * N;
    for (int k = threadIdx.x; k < N; k += blockDim.x) {
      float w = wr[k];
      if (w != 0.0f) {
        int slot = atomicAdd(&scnt, 1);
        if (slot < CAP) {
          cols[row * CAP + slot] = k;
          wts[row * CAP + slot] = w;
        }
      }
    }
  }
  // ---- X LLC-warm pass (formerly touch_kernel) ----
  {
    long i = (long)blockIdx.x * blockDim.x + threadIdx.x;
    const long stride = (long)gridDim.x * blockDim.x;
    float acc = 0.f;
    for (; i < n4; i += stride) {
      float4 v = x4[i];
      acc += v.x + v.y + v.z + v.w;
    }
    if (acc == 1234.56789f) dump[blockIdx.x & 1023] = acc;  // defeat DCE
  }
  __syncthreads();
  if (threadIdx.x == 0 && row < N) {
    cnts[row] = scnt;
    if (scnt == 0) { cols[row * CAP] = 0; wts[row * CAP] = 0.0f; }
  }
}

// ---------------------------------------------------------------------------
// Kernel 3: producer/consumer, minimal-instruction compute wave.
//   EXACT R5 structure (measured 333/331 us in R5/R13; best of 13 rounds).
//   Perturbation ledger (all regressed): VOP3P packed (R8) 405; b64+K64
//   (R10) 363; f32x2 obuf (R7) 440 [4-way bank conflict]; fused decode (R9)
//   1507 [atomic contention on barrier-coupled wave]; no-touch (R11) 398;
//   distance-2 loader (R12) 428 [compiler refuses the pipeline].
//     wave0 (compute): 16 VALU + 1 ds_read_b32 (I) + 2 ds_write_b32 = 19/step
//       at the measured ~5.1 cyc/inst solo-wave cadence -> ~97 cyc/step.
//       - I = w*x precomputed by the loader, read via imm-offset ds_read.
//       - Writes PRE-reset vn and PRE-jump un; writers re-derive the spike.
//       - sp = (vn > thn) is bitwise-equivalent to ((vn-thn) > 0) in IEEE.
//     wave1 (loader + s-writer): loads x (LLC-warm), I=w*x -> ibuf (dbuf,
//       one batch ahead); recomputes s from obuf.vn and stores.
//     wave2 (v-writer): v_out = sp ? c : vn.   wave3 (u-writer): un + sp?d:0.
//   All LDS conflict-free (measured 0): scalar planes, float4 reads at 16B
//   stride (32B stride = 4-way conflict, R7's bug).
//   Sync = raw s_barrier + lgkmcnt(0) only; writer stores stay in flight.
// ---------------------------------------------------------------------------
__global__ void __launch_bounds__(256) izh_pc3_kernel(
    const float* __restrict__ X, const float* __restrict__ state,
    const float* __restrict__ a, const float* __restrict__ b,
    const float* __restrict__ c, const float* __restrict__ d,
    const float* __restrict__ th, const float* __restrict__ dtv,
    const float* __restrict__ W1,
    const int* __restrict__ cnts, const int* __restrict__ cols,
    const float* __restrict__ wts,
    float* __restrict__ o_s, float* __restrict__ o_st,
    int T, int N)
{
#pragma clang fp contract(off)
  __shared__ float ibuf[2][K][64];        // staged I = w*x   (16 KB)
  __shared__ float obuf[2][K][2][64];     // staged vn,un     (32 KB)
  __shared__ int s_fast;

  const int wid  = threadIdx.x >> 6;
  const int lane = threadIdx.x & 63;
  const int base = blockIdx.x * 64;
  const int gn   = base + lane;
  const long N2  = 2L * N;
  const int B    = T / K;

  // ---- block-uniform path decision ----
  if (wid == 0) {
    bool elig = (base + 64 <= N);
    if (elig) elig = (cnts[gn] == 1) && (dtv[gn] == 1.0f);
    unsigned long long m = __ballot(elig);
    if (lane == 0) s_fast = (m == ~0ULL) ? 1 : 0;
  }
  __syncthreads();

  if (s_fast) {
    // ---- prologue: loader fills ibuf[0] (batch 0) ----
    if (wid == 1) {
      const float wn = wts[gn * CAP];
      const int   c0 = cols[gn * CAP];
      const float* Xp = X + c0;
      float xr[K];
#pragma unroll
      for (int i = 0; i < K; ++i) xr[i] = Xp[(size_t)i * N];
#pragma unroll
      for (int i = 0; i < K; ++i) ibuf[0][i][lane] = wn * xr[i];
    }
    __syncthreads();   // one-time full sync (vmcnt drain OK outside loop)

    if (wid == 0) {
      // ================= compute wave =================
      float v = state[gn], u = state[N + gn];
      const float bn = b[gn], cn = c[gn], dn = d[gn], thn = th[gn];
      const float Pn = dtv[gn] * a[gn];   // same operands/order as ref's dt*a

      for (int k = 0; k < B; ++k) {
        const int bsel = k & 1;
#pragma unroll
        for (int i = 0; i < K; ++i) {
          const float I = ibuf[bsel][i][lane];     // 1 ds_read, imm offset
          float t1 = 0.04f * v;
          float t2 = t1 * v;
          float t3 = 5.0f * v;
          float t4 = t2 + t3;
          float t5 = t4 + 140.0f;
          float t6 = t5 - u;
          float t7 = t6 + I;
          float vn = v + t7;      /* dt==1: exact */
          float q1 = bn * v;
          float q2 = q1 - u;
          float q3 = Pn * q2;
          float un = u + q3;
          obuf[bsel][i][0][lane] = vn;             // pre-reset v
          obuf[bsel][i][1][lane] = un;             // pre-jump u
          bool sp = vn > thn;     /* == (vn-thn)>0 bitwise (IEEE) */
          v = sp ? cn : vn;
          u = un + (sp ? dn : 0.0f);
        }
        asm volatile("s_waitcnt lgkmcnt(0)" ::: "memory");
        __builtin_amdgcn_s_barrier();
      }

      // tail (T % K != 0): direct global path (none for T=8192,K=32)
      if (B * K < T) {
        const float w0 = wts[gn * CAP];
        const float* Xp = X + cols[gn * CAP];
        for (int t = B * K; t < T; ++t) {
          const float I = w0 * Xp[(size_t)t * N];
          float t1 = 0.04f * v; float t2 = t1 * v; float t3 = 5.0f * v;
          float t4 = t2 + t3; float t5 = t4 + 140.0f; float t6 = t5 - u;
          float t7 = t6 + I; float vn = v + t7;
          float q1 = bn * v; float q2 = q1 - u; float q3 = Pn * q2;
          float un = u + q3;
          bool sp = vn > thn;
          v = sp ? cn : vn; u = un + (sp ? dn : 0.0f);
          o_s[(long)t * N + gn] = sp ? 1.0f : 0.0f;
          o_st[(long)t * N2 + gn] = v;
          o_st[(long)t * N2 + N + gn] = u;
        }
      }
    } else if (wid == 1) {
      // ================= loader + s-writer =================
      const float wn = wts[gn * CAP];
      const int   c0 = cols[gn * CAP];
      const float* Xp = X + c0;
      const int r = lane >> 4, j = lane & 15;
      const float4 th4 = *(const float4*)&th[base + 4 * j];

      for (int k = 0; k < B; ++k) {
        if (k + 1 < B) {                    // stage I for batch k+1
          float xr[K];
#pragma unroll
          for (int i = 0; i < K; ++i) xr[i] = Xp[(size_t)((k + 1) * K + i) * N];
#pragma unroll
          for (int i = 0; i < K; ++i) ibuf[(k + 1) & 1][i][lane] = wn * xr[i];
        }
        if (k > 0) {                        // s-store batch k-1
          const int q = k - 1, bsel = q & 1, t0 = q * K;
#pragma unroll
          for (int i = 0; i < K; i += 4) {
            float4 vn4 = *(const float4*)&obuf[bsel][i + r][0][4 * j];
            float4 s4;
            s4.x = vn4.x > th4.x ? 1.0f : 0.0f;
            s4.y = vn4.y > th4.y ? 1.0f : 0.0f;
            s4.z = vn4.z > th4.z ? 1.0f : 0.0f;
            s4.w = vn4.w > th4.w ? 1.0f : 0.0f;
            *(float4*)(o_s + (size_t)(t0 + i + r) * N + base + 4 * j) = s4;
          }
        }
        asm volatile("s_waitcnt lgkmcnt(0)" ::: "memory");
        __builtin_amdgcn_s_barrier();
      }
      if (B > 0) {                          // drain s for batch B-1
        const int q = B - 1, bsel = q & 1, t0 = q * K;
#pragma unroll
        for (int i = 0; i < K; i += 4) {
          float4 vn4 = *(const float4*)&obuf[bsel][i + r][0][4 * j];
          float4 s4;
          s4.x = vn4.x > th4.x ? 1.0f : 0.0f;
          s4.y = vn4.y > th4.y ? 1.0f : 0.0f;
          s4.z = vn4.z > th4.z ? 1.0f : 0.0f;
          s4.w = vn4.w > th4.w ? 1.0f : 0.0f;
          *(float4*)(o_s + (size_t)(t0 + i + r) * N + base + 4 * j) = s4;
        }
      }
    } else if (wid == 2) {
      // ================= v-writer: v_out = sp ? c : vn =================
      const int r = lane >> 4, j = lane & 15;
      const float4 th4 = *(const float4*)&th[base + 4 * j];
      const float4 c4  = *(const float4*)&c[base + 4 * j];

      for (int k = 0; k < B; ++k) {
        if (k > 0) {
          const int q = k - 1, bsel = q & 1, t0 = q * K;
#pragma unroll
          for (int i = 0; i < K; i += 4) {
            float4 vn4 = *(const float4*)&obuf[bsel][i + r][0][4 * j];
            float4 o4;
            o4.x = vn4.x > th4.x ? c4.x : vn4.x;
            o4.y = vn4.y > th4.y ? c4.y : vn4.y;
            o4.z = vn4.z > th4.z ? c4.z : vn4.z;
            o4.w = vn4.w > th4.w ? c4.w : vn4.w;
            *(float4*)(o_st + (size_t)(t0 + i + r) * N2 + base + 4 * j) = o4;
          }
        }
        __builtin_amdgcn_s_barrier();
      }
      if (B > 0) {
        const int q = B - 1, bsel = q & 1, t0 = q * K;
#pragma unroll
        for (int i = 0; i < K; i += 4) {
          float4 vn4 = *(const float4*)&obuf[bsel][i + r][0][4 * j];
          float4 o4;
          o4.x = vn4.x > th4.x ? c4.x : vn4.x;
          o4.y = vn4.y > th4.y ? c4.y : vn4.y;
          o4.z = vn4.z > th4.z ? c4.z : vn4.z;
          o4.w = vn4.w > th4.w ? c4.w : vn4.w;
          *(float4*)(o_st + (size_t)(t0 + i + r) * N2 + base + 4 * j) = o4;
        }
      }
    } else {
      // ================= u-writer: u_out = un + (sp ? d : 0) =============
      const int r = lane >> 4, j = lane & 15;
      const float4 th4 = *(const float4*)&th[base + 4 * j];
      const float4 d4  = *(const float4*)&d[base + 4 * j];

      for (int k = 0; k < B; ++k) {
        if (k > 0) {
          const int q = k - 1, bsel = q & 1, t0 = q * K;
#pragma unroll
          for (int i = 0; i < K; i += 4) {
            float4 vn4 = *(const float4*)&obuf[bsel][i + r][0][4 * j];
            float4 un4 = *(const float4*)&obuf[bsel][i + r][1][4 * j];
            float4 o4;
            o4.x = un4.x + (vn4.x > th4.x ? d4.x : 0.0f);
            o4.y = un4.y + (vn4.y > th4.y ? d4.y : 0.0f);
            o4.z = un4.z + (vn4.z > th4.z ? d4.z : 0.0f);
            o4.w = un4.w + (vn4.w > th4.w ? d4.w : 0.0f);
            *(float4*)(o_st + (size_t)(t0 + i + r) * N2 + N + base + 4 * j) = o4;
          }
        }
        __builtin_amdgcn_s_barrier();
      }
      if (B > 0) {
        const int q = B - 1, bsel = q & 1, t0 = q * K;
#pragma unroll
        for (int i = 0; i < K; i += 4) {
          float4 vn4 = *(const float4*)&obuf[bsel][i + r][0][4 * j];
          float4 un4 = *(const float4*)&obuf[bsel][i + r][1][4 * j];
          float4 o4;
          o4.x = un4.x + (vn4.x > th4.x ? d4.x : 0.0f);
          o4.y = un4.y + (vn4.y > th4.y ? d4.y : 0.0f);
          o4.z = un4.z + (vn4.z > th4.z ? d4.z : 0.0f);
          o4.w = un4.w + (vn4.w > th4.w ? d4.w : 0.0f);
          *(float4*)(o_st + (size_t)(t0 + i + r) * N2 + N + base + 4 * j) = o4;
        }
      }
    }
  } else {
    // ---- general fallback: wave0 threads only, any cnt / dt ----
    if (wid != 0 || gn >= N) return;
    float v = state[gn], u = state[N + gn];
    const float an = a[gn], bn = b[gn], cn = c[gn], dn = d[gn];
    const float thn = th[gn], dtn = dtv[gn];
    const float Pn = dtn * an;
    const int cnt = cnts[gn];
    for (int t = 0; t < T; ++t) {
      float I = 0.0f;
      if (cnt <= CAP) {
        for (int j = 0; j < cnt; ++j)
          I = I + wts[gn * CAP + j] * X[(size_t)t * N + cols[gn * CAP + j]];
      } else {
        const float* wr = W1 + (size_t)gn * N;
        const float* xr = X + (size_t)t * N;
        for (int kk = 0; kk < N; ++kk) I = I + wr[kk] * xr[kk];
      }
      float t1 = 0.04f * v; float t2 = t1 * v; float t3 = 5.0f * v;
      float t4 = t2 + t3; float t5 = t4 + 140.0f; float t6 = t5 - u;
      float t7 = t6 + I; float t8 = dtn * t7; float vn = v + t8;
      float q1 = bn * v; float q2 = q1 - u; float q3 = Pn * q2; float un = u + q3;
      float df = vn - thn; bool sp = df > 0.0f;
      v = sp ? cn : vn; u = un + (sp ? dn : 0.0f);
      o_s[(size_t)t * N + gn] = sp ? 1.0f : 0.0f;
      o_st[(size_t)t * N2 + gn] = v;
      o_st[(size_t)t * N2 + N + gn] = u;
    }
  }
}

// ---------------------------------------------------------------------------
// Kernel 4: r[t] = W2 @ s[t], grid-stride over t (exact: terms are 20*{0,1},
// integer sums < 2^24 are order-independent).
// ---------------------------------------------------------------------------
__global__ void decode_dot_kernel(const float* __restrict__ o_s,
                                  const float* __restrict__ W2,
                                  float* __restrict__ r, int T, int N) {
  __shared__ float red[4];
  for (int t = blockIdx.x; t < T; t += gridDim.x) {
    const float* srow = o_s + (long)t * N;
    float p = 0.0f;
    for (int n = threadIdx.x; n < N; n += blockDim.x)
      p += W2[n] * srow[n];
    for (int off = 32; off > 0; off >>= 1) p += __shfl_down(p, off);
    if ((threadIdx.x & 63) == 0) red[threadIdx.x >> 6] = p;
    __syncthreads();
    if (threadIdx.x == 0) {
      float tot = 0.f;
      const int nw = blockDim.x >> 6;
      for (int w = 0; w < nw; ++w) tot += red[w];
      r[t] = tot;
    }
    __syncthreads();
  }
}

// ---------------------------------------------------------------------------
// Kernel 5: dm[t] = leak*dm[t-1] + r[t], chunked affine scan (1 block, 64 thr)
// ---------------------------------------------------------------------------
__global__ void decode_scan_kernel(const float* __restrict__ r,
                                   const float* __restrict__ leakp,
                                   float* __restrict__ out, int T) {
  __shared__ float Bsh[64], Ssh[64];
  const float leakv = leakp[0];
  const int i = threadIdx.x;                 // 0..63
  const int chunk = (T + 63) / 64;
  const int t0 = i * chunk;
  float B = 0.0f;
  for (int j = 0; j < chunk; ++j) {
    int t = t0 + j;
    if (t < T) B = leakv * B + r[t];
  }
  Bsh[i] = B;
  float A = 1.0f, p = leakv; int e = chunk;
  while (e) { if (e & 1) A *= p; p *= p; e >>= 1; }
  __syncthreads();
  if (i == 0) {
    float dm = 0.0f;
    for (int k = 0; k < 64; ++k) { Ssh[k] = dm; dm = A * dm + Bsh[k]; }
  }
  __syncthreads();
  float dm = Ssh[i];
  for (int j = 0; j < chunk; ++j) {
    int t = t0 + j;
    if (t < T) { dm = leakv * dm + r[t]; out[t] = dm; }
  }
}

// ---------------------------------------------------------------------------
extern "C" void kernel_launch(void* const* d_in, const int* in_sizes, int n_in,
                              void* d_out, int out_size, void* d_ws, size_t ws_size,
                              hipStream_t stream) {
  const float* X  = (const float*)d_in[0];
  const float* st = (const float*)d_in[1];
  const float* W1 = (const float*)d_in[2];
  const float* W2 = (const float*)d_in[3];
  const float* a  = (const float*)d_in[4];
  const float* b  = (const float*)d_in[5];
  const float* c  = (const float*)d_in[6];
  const float* d  = (const float*)d_in[7];
  const float* th = (const float*)d_in[8];
  const float* dt = (const float*)d_in[9];
  const float* lk = (const float*)d_in[10];
  const int N = in_sizes[4];          // a has N elements
  const int T = in_sizes[0] / N;

  float* o_s  = (float*)d_out;               // outputs  [T,N]
  float* o_st = o_s + (long)T * N;           // states   [T,2,N]
  float* o_dm = o_st + 2L * (long)T * N;     // decoded  [T,1]

  int*   cnts = (int*)d_ws;                  // N
  int*   cols = cnts + N;                    // N*CAP
  float* wts  = (float*)(cols + (long)N * CAP); // N*CAP
  float* rbuf = wts + (long)N * CAP;         // T
  float* dump = rbuf + T;                    // toucher sink

  const long n4 = ((long)T * N) / 4;
  sparsify_touch_kernel<<<N, 256, 0, stream>>>(W1, N, cnts, cols, wts,
                                               (const float4*)X, n4, dump);
  const int nblk = (N + 63) / 64;
  izh_pc3_kernel<<<nblk, 256, 0, stream>>>(X, st, a, b, c, d, th, dt, W1,
                                           cnts, cols, wts, o_s, o_st, T, N);
  const int ndec = (T < 2048) ? T : 2048;
  decode_dot_kernel<<<ndec, 256, 0, stream>>>(o_s, W2, rbuf, T, N);
  decode_scan_kernel<<<1, 64, 0, stream>>>(rbuf, lk, o_dm, T);
}